// Round 7
// baseline (85.498 us; speedup 1.0000x reference)
//
#include <hip/hip_runtime.h>
#include <hip/hip_fp16.h>

typedef _Float16 half8 __attribute__((ext_vector_type(8)));
typedef _Float16 half4v __attribute__((ext_vector_type(4)));
typedef _Float16 half2v __attribute__((ext_vector_type(2)));
typedef float f32x4 __attribute__((ext_vector_type(4)));

#define N_INNER 511
#define NPAD 512
#define FEAT 1024
#define BATCH 16384
#define NCLS 100
#define NCLSPAD 112

#define AS1 __attribute__((address_space(1)))
#define AS3 __attribute__((address_space(3)))

// ---------------- prep: W -> Wh f16 [512][1024] (row 511 zero); L -> LT f16 [112][512] ----------------
__global__ void k_prep(const float* __restrict__ W, const float* __restrict__ L,
                       _Float16* __restrict__ Wh, _Float16* __restrict__ LT) {
  const int i = blockIdx.x * 256 + threadIdx.x;

  if (i < 65536) {  // Wh: 524,288 elems, 8 per thread
    const int off = i * 8;
    const int row = off >> 10;
    half8 h;
    if (row < N_INNER) {
      const f32x4 a = *(const f32x4*)(W + off);
      const f32x4 b = *(const f32x4*)(W + off + 4);
      h[0] = (_Float16)a[0]; h[1] = (_Float16)a[1]; h[2] = (_Float16)a[2]; h[3] = (_Float16)a[3];
      h[4] = (_Float16)b[0]; h[5] = (_Float16)b[1]; h[6] = (_Float16)b[2]; h[7] = (_Float16)b[3];
    } else {
      h = (half8)(_Float16)0.f;
    }
    *(half8*)(Wh + off) = h;
  }

  if (i < NCLSPAD * NPAD) {  // LT transpose-pad
    const int n = i >> 9, k = i & 511;
    LT[i] = (n < NCLS) ? (_Float16)L[(size_t)k * NCLS + n] : (_Float16)0.f;
  }
}

// ---------------- GEMM1: gates = sigmoid(x @ Wh^T + b), heap-layout f16 out [16384][512] ----------------
// Tile 64x512 (full N), BK=32, 32 iters, grid 256, 512 threads (8 waves, each owns 64 cols).
// x: NON-TEMPORAL f32x4 loads (block-private, don't thrash L2) -> reg -> f16 LDS (stride 36).
// Wh: normal-cached global_load_lds (stays L2-resident), XOR-swizzled source chunks, linear LDS dest.
// gates: non-temporal stores.
#define LDA 36

__global__ __launch_bounds__(512, 2) void k_gemm1(
    const float* __restrict__ x, const _Float16* __restrict__ Wh,
    const float* __restrict__ bias, _Float16* __restrict__ gates) {
  __shared__ _Float16 lB[2][512 * 32];  // 64 KB total
  __shared__ _Float16 lA[2][64 * LDA];  // 9 KB total

  const int t = threadIdx.x;
  const int lane = t & 63;
  const int w = t >> 6;          // wave 0..7 owns output cols w*64..+63
  const int bm = blockIdx.x;     // 256 blocks x 64 rows

  // ---- A staging: thread t owns (row t>>3, 4-col seg t&7) of the 64x32 f32 subtile
  const float* pa = x + (size_t)(bm * 64 + (t >> 3)) * FEAT + (t & 7) * 4;
  const int aoff = (t >> 3) * LDA + (t & 7) * 4;  // byte = row*72 + seg*8 (8B aligned)

  // ---- B staging: 4 calls/iter; call i covers rows i*128..+127.
  //      LDS byte L = i*8192 + w*1024 + lane*16 -> row = i*128 + w*16 + (lane>>2), dest chunk c' = lane&3.
  //      swizzle: chunk stored at c' = c ^ ((row>>1)&3) -> source chunk c = (lane&3) ^ ((lane>>3)&3).
  const int brow = w * 16 + (lane >> 2);
  const int bc = (lane & 3) ^ ((lane >> 3) & 3);
  const _Float16* pb = Wh + (size_t)brow * FEAT + bc * 8;

  f32x4 acc[4][4] = {};
  f32x4 ra;

  auto a_load = [&](int k0) {
    ra = __builtin_nontemporal_load((const f32x4*)(pa + k0));
  };
  auto a_write = [&](int B) {
    half4v h;
    h[0] = (_Float16)ra[0]; h[1] = (_Float16)ra[1]; h[2] = (_Float16)ra[2]; h[3] = (_Float16)ra[3];
    *(half4v*)&lA[B][aoff] = h;
  };
  auto b_stage = [&](int k0, int B) {
#pragma unroll
    for (int i = 0; i < 4; ++i)
      __builtin_amdgcn_global_load_lds((const AS1 void*)(pb + (size_t)i * 128 * FEAT + k0),
                                       (AS3 void*)((char*)&lB[B][0] + i * 8192 + w * 1024),
                                       16, 0, 0);
  };

  // prologue
  a_load(0);
  b_stage(0, 0);
  a_write(0);
  __syncthreads();

  for (int kk = 0; kk < 32; ++kk) {
    const int cur = kk & 1;
    if (kk < 31) {
      b_stage((kk + 1) * 32, cur ^ 1);  // issue first: latency hides under MFMA
      a_load((kk + 1) * 32);
    }

    half8 af[4], bf[4];
#pragma unroll
    for (int i = 0; i < 4; ++i)
      af[i] = *(const half8*)&lA[cur][(i * 16 + (lane & 15)) * LDA + (lane >> 4) * 8];
#pragma unroll
    for (int j = 0; j < 4; ++j) {
      const int row = w * 64 + j * 16 + (lane & 15);
      const int cc = (lane >> 4) ^ ((lane >> 1) & 3);  // un-swizzle
      bf[j] = *(const half8*)&lB[cur][row * 32 + cc * 8];
    }
#pragma unroll
    for (int i = 0; i < 4; ++i)
#pragma unroll
      for (int j = 0; j < 4; ++j)
        acc[i][j] = __builtin_amdgcn_mfma_f32_16x16x32_f16(af[i], bf[j], acc[i][j], 0, 0, 0);

    if (kk < 31) a_write(cur ^ 1);  // cvt + ds_write after compute
    __syncthreads();                 // drains vmcnt (B) + lgkm (A)
  }

  // epilogue: bias + sigmoid, store f16 (non-temporal) to heap position (col+1)&511
#pragma unroll
  for (int j = 0; j < 4; ++j) {
    const int col = w * 64 + j * 16 + (lane & 15);
    const float bb = (col < N_INNER) ? bias[col] : 0.f;
    const int hpos = (col + 1) & 511;
#pragma unroll
    for (int i = 0; i < 4; ++i) {
      const int rowb = bm * 64 + i * 16 + ((lane >> 4) << 2);
#pragma unroll
      for (int r = 0; r < 4; ++r) {
        float v = acc[i][j][r] + bb;
        v = 1.f / (1.f + __expf(-v));
        __builtin_nontemporal_store((_Float16)v, &gates[(size_t)(rowb + r) * NPAD + hpos]);
      }
    }
  }
}

// ---------------- K2: tree expansion + GEMM2 (prob @ leaf_logits) ----------------
#define LPS 520

__global__ __launch_bounds__(512, 4) void k_tree(
    const _Float16* __restrict__ gates, const _Float16* __restrict__ LT,
    float* __restrict__ out) {
  __shared__ _Float16 lp[32 * LPS];

  const int t = threadIdx.x;
  const int rowl = t >> 4, sub = t & 15;
  const size_t grow = (size_t)blockIdx.x * 32 + rowl;
  const _Float16* g = gates + grow * NPAD;

  const float f0 = (float)g[1];
  const float f1 = (float)g[2 + (sub >> 3)];
  const float f2 = (float)g[4 + (sub >> 2)];
  const float f3 = (float)g[8 + (sub >> 1)];
  const _Float16 g4 = g[16 + sub];
  const half2v g5 = *(const half2v*)(g + 32 + 2 * sub);
  const half4v g6 = *(const half4v*)(g + 64 + 4 * sub);
  const half8 g7 = *(const half8*)(g + 128 + 8 * sub);
  const half8 g8a = *(const half8*)(g + 256 + 16 * sub);
  const half8 g8b = *(const half8*)(g + 256 + 16 * sub + 8);

  float p = ((sub & 8) ? f0 : 1.f - f0) * ((sub & 4) ? f1 : 1.f - f1) *
            ((sub & 2) ? f2 : 1.f - f2) * ((sub & 1) ? f3 : 1.f - f3);

  float arr[32];
  {
    const float gg = (float)g4;
    arr[1] = p * gg; arr[0] = p - p * gg;
  }
#pragma unroll
  for (int i = 1; i >= 0; --i) {
    const float gg = (float)g5[i];
    const float pp = arr[i];
    arr[2 * i + 1] = pp * gg; arr[2 * i] = pp - pp * gg;
  }
#pragma unroll
  for (int i = 3; i >= 0; --i) {
    const float gg = (float)g6[i];
    const float pp = arr[i];
    arr[2 * i + 1] = pp * gg; arr[2 * i] = pp - pp * gg;
  }
#pragma unroll
  for (int i = 7; i >= 0; --i) {
    const float gg = (float)g7[i];
    const float pp = arr[i];
    arr[2 * i + 1] = pp * gg; arr[2 * i] = pp - pp * gg;
  }
#pragma unroll
  for (int i = 15; i >= 0; --i) {
    const float gg = (i < 8) ? (float)g8a[i] : (float)g8b[i - 8];
    const float pp = arr[i];
    arr[2 * i + 1] = pp * gg; arr[2 * i] = pp - pp * gg;
  }

  const int lb = sub * 32;
#pragma unroll
  for (int i = 0; i < 32; i += 8) {
    half8 h;
#pragma unroll
    for (int jj = 0; jj < 8; ++jj) h[jj] = (_Float16)arr[i + jj];
    *(half8*)&lp[rowl * LPS + lb + i] = h;
  }
  __syncthreads();

  const int lane = t & 63, w = t >> 6;
  if (w < 7) {
    f32x4 acc[2] = {};
#pragma unroll
    for (int k0 = 0; k0 < 512; k0 += 32) {
      const int n = w * 16 + (lane & 15);
      const half8 b8 = *(const half8*)&LT[(size_t)n * NPAD + k0 + (lane >> 4) * 8];
#pragma unroll
      for (int mf = 0; mf < 2; ++mf) {
        const half8 a = *(const half8*)&lp[(mf * 16 + (lane & 15)) * LPS + k0 + (lane >> 4) * 8];
        acc[mf] = __builtin_amdgcn_mfma_f32_16x16x32_f16(a, b8, acc[mf], 0, 0, 0);
      }
    }

    const int col = w * 16 + (lane & 15);
    if (col < NCLS) {
#pragma unroll
      for (int mf = 0; mf < 2; ++mf) {
        const int rowb = blockIdx.x * 32 + mf * 16 + ((lane >> 4) << 2);
#pragma unroll
        for (int r = 0; r < 4; ++r)
          out[(size_t)(rowb + r) * NCLS + col] = acc[mf][r];
      }
    }
  }
}

extern "C" void kernel_launch(void* const* d_in, const int* in_sizes, int n_in,
                              void* d_out, int out_size, void* d_ws, size_t ws_size,
                              hipStream_t stream) {
  const float* x = (const float*)d_in[0];
  const float* W = (const float*)d_in[1];
  const float* b = (const float*)d_in[2];
  const float* L = (const float*)d_in[3];
  float* out = (float*)d_out;

  char* ws = (char*)d_ws;
  _Float16* Wh    = (_Float16*)ws;                 // 1 MB @ 0
  _Float16* LT    = (_Float16*)(ws + (1u << 20));  // 112 KB @ 1 MB
  _Float16* gates = (_Float16*)(ws + (2u << 20));  // 16 MB @ 2 MB

  k_prep<<<256, 256, 0, stream>>>(W, L, Wh, LT);
  k_gemm1<<<256, 512, 0, stream>>>(x, Wh, b, gates);
  k_tree<<<512, 512, 0, stream>>>(gates, LT, out);
}

// Round 8
// 61.818 us; speedup vs baseline: 1.3831x; 1.3831x over previous
//
#include <hip/hip_runtime.h>
#include <hip/hip_fp16.h>

typedef _Float16 half8 __attribute__((ext_vector_type(8)));
typedef _Float16 half4v __attribute__((ext_vector_type(4)));
typedef _Float16 half2v __attribute__((ext_vector_type(2)));
typedef float f32x4 __attribute__((ext_vector_type(4)));

#define N_INNER 511
#define NPAD 512
#define FEAT 1024
#define BATCH 16384
#define NCLS 100
#define NCLSPAD 112

#define AS1 __attribute__((address_space(1)))
#define AS3 __attribute__((address_space(3)))

// ---------------- prep: W -> Wh f16 [512][1024] (row 511 zero); L -> LT f16 [112][512] ----------------
__global__ void k_prep(const float* __restrict__ W, const float* __restrict__ L,
                       _Float16* __restrict__ Wh, _Float16* __restrict__ LT) {
  const int i = blockIdx.x * 256 + threadIdx.x;

  if (i < 65536) {  // Wh: 524,288 elems, 8 per thread
    const int off = i * 8;
    const int row = off >> 10;
    half8 h;
    if (row < N_INNER) {
      const f32x4 a = *(const f32x4*)(W + off);
      const f32x4 b = *(const f32x4*)(W + off + 4);
      h[0] = (_Float16)a[0]; h[1] = (_Float16)a[1]; h[2] = (_Float16)a[2]; h[3] = (_Float16)a[3];
      h[4] = (_Float16)b[0]; h[5] = (_Float16)b[1]; h[6] = (_Float16)b[2]; h[7] = (_Float16)b[3];
    } else {
      h = (half8)(_Float16)0.f;
    }
    *(half8*)(Wh + off) = h;
  }

  if (i < NCLSPAD * NPAD) {  // LT transpose-pad
    const int n = i >> 9, k = i & 511;
    LT[i] = (n < NCLS) ? (_Float16)L[(size_t)k * NCLS + n] : (_Float16)0.f;
  }
}

// ---------------- GEMM1: gates = sigmoid(x @ Wh^T + b), heap-layout f16 out [16384][512] ----------------
// Tile 64(M)x256(N), BK=32, 256 threads (4 waves, wave 64x64), dbuf, 3 blocks/CU (LDS 42 KB).
// B: global_load_lds, XOR source-swizzle (verified R7: conflict-free reads), linear LDS [256][32].
// A: f32x4 reg-staged -> f16 LDS stride 40 (16B-aligned rows, 2-way banks = free).
#define LDA 40

__global__ __launch_bounds__(256, 3) void k_gemm1(
    const float* __restrict__ x, const _Float16* __restrict__ Wh,
    const float* __restrict__ bias, _Float16* __restrict__ gates) {
  __shared__ _Float16 lB[2][256 * 32];  // 32 KB total
  __shared__ _Float16 lA[2][64 * LDA];  // 10.25 KB total

  const int t = threadIdx.x;
  const int lane = t & 63;
  const int w = t >> 6;          // wave 0..3 owns output cols w*64..+63 (of the 256-col tile)

  // XCD swizzle: each XCD gets a contiguous bm-range with both bn-siblings
  const int bid = blockIdx.x;          // grid 512
  const int xcd = bid & 7, idx = bid >> 3;   // idx 0..63
  const int bm = xcd * 32 + (idx >> 1);      // 0..255
  const int bn = idx & 1;                    // 0..1

  // ---- A staging: 512 f32x4 tasks (row 0..63, seg 0..7); thread does t and t+256
  const int r0 = t >> 3, s0 = t & 7;
  const int r1 = (t + 256) >> 3, s1 = (t + 256) & 7;
  const float* pa0 = x + (size_t)(bm * 64 + r0) * FEAT + s0 * 4;
  const float* pa1 = x + (size_t)(bm * 64 + r1) * FEAT + s1 * 4;
  const int aoff0 = r0 * LDA + s0 * 4;
  const int aoff1 = r1 * LDA + s1 * 4;

  // ---- B staging: 4 calls/iter; call i: LDS byte = i*4096 + w*1024 + lane*16
  //      row = i*64 + w*16 + (lane>>2), dest chunk c' = lane&3; source chunk c = c' ^ ((row>>1)&3)
  //      = (lane&3) ^ ((lane>>3)&3).
  const int brow = w * 16 + (lane >> 2);
  const int bc = (lane & 3) ^ ((lane >> 3) & 3);
  const _Float16* pb = Wh + (size_t)(bn * 256 + brow) * FEAT + bc * 8;

  f32x4 acc[4][4] = {};
  f32x4 ra0, ra1;

  auto a_load = [&](int k0) {
    ra0 = *(const f32x4*)(pa0 + k0);
    ra1 = *(const f32x4*)(pa1 + k0);
  };
  auto a_write = [&](int B) {
    half4v h0, h1;
    h0[0] = (_Float16)ra0[0]; h0[1] = (_Float16)ra0[1]; h0[2] = (_Float16)ra0[2]; h0[3] = (_Float16)ra0[3];
    h1[0] = (_Float16)ra1[0]; h1[1] = (_Float16)ra1[1]; h1[2] = (_Float16)ra1[2]; h1[3] = (_Float16)ra1[3];
    *(half4v*)&lA[B][aoff0] = h0;
    *(half4v*)&lA[B][aoff1] = h1;
  };
  auto b_stage = [&](int k0, int B) {
#pragma unroll
    for (int i = 0; i < 4; ++i)
      __builtin_amdgcn_global_load_lds((const AS1 void*)(pb + (size_t)i * 64 * FEAT + k0),
                                       (AS3 void*)((char*)&lB[B][0] + i * 4096 + w * 1024),
                                       16, 0, 0);
  };

  // prologue
  a_load(0);
  b_stage(0, 0);
  a_write(0);
  __syncthreads();

  for (int kk = 0; kk < 32; ++kk) {
    const int cur = kk & 1;
    if (kk < 31) {
      b_stage((kk + 1) * 32, cur ^ 1);  // issue first: latency hides under MFMA
      a_load((kk + 1) * 32);
    }

    half8 af[4], bf[4];
#pragma unroll
    for (int i = 0; i < 4; ++i)
      af[i] = *(const half8*)&lA[cur][(i * 16 + (lane & 15)) * LDA + (lane >> 4) * 8];
#pragma unroll
    for (int j = 0; j < 4; ++j) {
      const int row = w * 64 + j * 16 + (lane & 15);
      const int cc = (lane >> 4) ^ ((lane >> 1) & 3);  // un-swizzle
      bf[j] = *(const half8*)&lB[cur][row * 32 + cc * 8];
    }
#pragma unroll
    for (int i = 0; i < 4; ++i)
#pragma unroll
      for (int j = 0; j < 4; ++j)
        acc[i][j] = __builtin_amdgcn_mfma_f32_16x16x32_f16(af[i], bf[j], acc[i][j], 0, 0, 0);

    if (kk < 31) a_write(cur ^ 1);  // cvt + ds_write after compute
    __syncthreads();                 // drains vmcnt (B) + lgkm (A)
  }

  // epilogue: bias + sigmoid, store f16 to heap position (col+1)&511
#pragma unroll
  for (int j = 0; j < 4; ++j) {
    const int col = bn * 256 + w * 64 + j * 16 + (lane & 15);
    const float bb = (col < N_INNER) ? bias[col] : 0.f;
    const int hpos = (col + 1) & 511;
#pragma unroll
    for (int i = 0; i < 4; ++i) {
      const int rowb = bm * 64 + i * 16 + ((lane >> 4) << 2);
#pragma unroll
      for (int r = 0; r < 4; ++r) {
        float v = acc[i][j][r] + bb;
        v = 1.f / (1.f + __expf(-v));
        gates[(size_t)(rowb + r) * NPAD + hpos] = (_Float16)v;
      }
    }
  }
}

// ---------------- K2: tree expansion + GEMM2 (prob @ leaf_logits) ----------------
#define LPS 520

__global__ __launch_bounds__(512, 4) void k_tree(
    const _Float16* __restrict__ gates, const _Float16* __restrict__ LT,
    float* __restrict__ out) {
  __shared__ _Float16 lp[32 * LPS];

  const int t = threadIdx.x;
  const int rowl = t >> 4, sub = t & 15;
  const size_t grow = (size_t)blockIdx.x * 32 + rowl;
  const _Float16* g = gates + grow * NPAD;

  const float f0 = (float)g[1];
  const float f1 = (float)g[2 + (sub >> 3)];
  const float f2 = (float)g[4 + (sub >> 2)];
  const float f3 = (float)g[8 + (sub >> 1)];
  const _Float16 g4 = g[16 + sub];
  const half2v g5 = *(const half2v*)(g + 32 + 2 * sub);
  const half4v g6 = *(const half4v*)(g + 64 + 4 * sub);
  const half8 g7 = *(const half8*)(g + 128 + 8 * sub);
  const half8 g8a = *(const half8*)(g + 256 + 16 * sub);
  const half8 g8b = *(const half8*)(g + 256 + 16 * sub + 8);

  float p = ((sub & 8) ? f0 : 1.f - f0) * ((sub & 4) ? f1 : 1.f - f1) *
            ((sub & 2) ? f2 : 1.f - f2) * ((sub & 1) ? f3 : 1.f - f3);

  float arr[32];
  {
    const float gg = (float)g4;
    arr[1] = p * gg; arr[0] = p - p * gg;
  }
#pragma unroll
  for (int i = 1; i >= 0; --i) {
    const float gg = (float)g5[i];
    const float pp = arr[i];
    arr[2 * i + 1] = pp * gg; arr[2 * i] = pp - pp * gg;
  }
#pragma unroll
  for (int i = 3; i >= 0; --i) {
    const float gg = (float)g6[i];
    const float pp = arr[i];
    arr[2 * i + 1] = pp * gg; arr[2 * i] = pp - pp * gg;
  }
#pragma unroll
  for (int i = 7; i >= 0; --i) {
    const float gg = (float)g7[i];
    const float pp = arr[i];
    arr[2 * i + 1] = pp * gg; arr[2 * i] = pp - pp * gg;
  }
#pragma unroll
  for (int i = 15; i >= 0; --i) {
    const float gg = (i < 8) ? (float)g8a[i] : (float)g8b[i - 8];
    const float pp = arr[i];
    arr[2 * i + 1] = pp * gg; arr[2 * i] = pp - pp * gg;
  }

  const int lb = sub * 32;
#pragma unroll
  for (int i = 0; i < 32; i += 8) {
    half8 h;
#pragma unroll
    for (int jj = 0; jj < 8; ++jj) h[jj] = (_Float16)arr[i + jj];
    *(half8*)&lp[rowl * LPS + lb + i] = h;
  }
  __syncthreads();

  const int lane = t & 63, w = t >> 6;
  if (w < 7) {
    f32x4 acc[2] = {};
#pragma unroll
    for (int k0 = 0; k0 < 512; k0 += 32) {
      const int n = w * 16 + (lane & 15);
      const half8 b8 = *(const half8*)&LT[(size_t)n * NPAD + k0 + (lane >> 4) * 8];
#pragma unroll
      for (int mf = 0; mf < 2; ++mf) {
        const half8 a = *(const half8*)&lp[(mf * 16 + (lane & 15)) * LPS + k0 + (lane >> 4) * 8];
        acc[mf] = __builtin_amdgcn_mfma_f32_16x16x32_f16(a, b8, acc[mf], 0, 0, 0);
      }
    }

    const int col = w * 16 + (lane & 15);
    if (col < NCLS) {
#pragma unroll
      for (int mf = 0; mf < 2; ++mf) {
        const int rowb = blockIdx.x * 32 + mf * 16 + ((lane >> 4) << 2);
#pragma unroll
        for (int r = 0; r < 4; ++r)
          out[(size_t)(rowb + r) * NCLS + col] = acc[mf][r];
      }
    }
  }
}

extern "C" void kernel_launch(void* const* d_in, const int* in_sizes, int n_in,
                              void* d_out, int out_size, void* d_ws, size_t ws_size,
                              hipStream_t stream) {
  const float* x = (const float*)d_in[0];
  const float* W = (const float*)d_in[1];
  const float* b = (const float*)d_in[2];
  const float* L = (const float*)d_in[3];
  float* out = (float*)d_out;

  char* ws = (char*)d_ws;
  _Float16* Wh    = (_Float16*)ws;                 // 1 MB @ 0
  _Float16* LT    = (_Float16*)(ws + (1u << 20));  // 112 KB @ 1 MB
  _Float16* gates = (_Float16*)(ws + (2u << 20));  // 16 MB @ 2 MB

  k_prep<<<256, 256, 0, stream>>>(W, L, Wh, LT);
  k_gemm1<<<512, 256, 0, stream>>>(x, Wh, b, gates);
  k_tree<<<512, 512, 0, stream>>>(gates, LT, out);
}

// Round 9
// 57.449 us; speedup vs baseline: 1.4882x; 1.0760x over previous
//
#include <hip/hip_runtime.h>
#include <hip/hip_fp16.h>

typedef _Float16 half8 __attribute__((ext_vector_type(8)));
typedef _Float16 half4v __attribute__((ext_vector_type(4)));
typedef _Float16 half2v __attribute__((ext_vector_type(2)));
typedef float f32x4 __attribute__((ext_vector_type(4)));

#define N_INNER 511
#define NPAD 512
#define FEAT 1024
#define BATCH 16384
#define NCLS 100
#define NCLSPAD 112

#define AS1 __attribute__((address_space(1)))
#define AS3 __attribute__((address_space(3)))

// ---------------- prep: W -> Wh f16 [512][1024] (row 511 zero); L -> LT f16 [112][512] ----------------
__global__ void k_prep(const float* __restrict__ W, const float* __restrict__ L,
                       _Float16* __restrict__ Wh, _Float16* __restrict__ LT) {
  const int i = blockIdx.x * 256 + threadIdx.x;

  if (i < 65536) {
    const int off = i * 8;
    const int row = off >> 10;
    half8 h;
    if (row < N_INNER) {
      const f32x4 a = *(const f32x4*)(W + off);
      const f32x4 b = *(const f32x4*)(W + off + 4);
      h[0] = (_Float16)a[0]; h[1] = (_Float16)a[1]; h[2] = (_Float16)a[2]; h[3] = (_Float16)a[3];
      h[4] = (_Float16)b[0]; h[5] = (_Float16)b[1]; h[6] = (_Float16)b[2]; h[7] = (_Float16)b[3];
    } else {
      h = (half8)(_Float16)0.f;
    }
    *(half8*)(Wh + off) = h;
  }

  if (i < NCLSPAD * NPAD) {
    const int n = i >> 9, k = i & 511;
    LT[i] = (n < NCLS) ? (_Float16)L[(size_t)k * NCLS + n] : (_Float16)0.f;
  }
}

// ---------------- GEMM1: gates = sigmoid(x @ Wh^T + b), heap-layout f16 out [16384][512] ----------------
// BM=64, BN=512 (full), BK=32, grid 256 (1 block/CU), 512 threads (8 waves, wave = 64x64).
// 4-buffer counted-vmcnt pipeline (T4): stage k+2 while computing k; s_waitcnt vmcnt(5) at the
// barrier (k+2's 4 B-gloads + 1 A-load stay in flight); raw s_barrier; never drain to 0 mid-loop.
// B: global_load_lds w/ verified XOR source-swizzle (conflict-free ds_read_b128).
// A: f32x4 reg-staged -> half4v ds_write, padded stride 40.
#define LDA 40

#define VM5  asm volatile("s_waitcnt vmcnt(5)" ::: "memory")
#define VM0  asm volatile("s_waitcnt vmcnt(0)" ::: "memory")
#define LG0  asm volatile("s_waitcnt lgkmcnt(0)" ::: "memory")
#define BARX __builtin_amdgcn_s_barrier()

__global__ __launch_bounds__(512, 1) void k_gemm1(
    const float* __restrict__ x, const _Float16* __restrict__ Wh,
    const float* __restrict__ bias, _Float16* __restrict__ gates) {
  __shared__ _Float16 lB[4][512 * 32];  // 4 x 32 KB
  __shared__ _Float16 lA[4][64 * LDA];  // 4 x 5.125 KB   -> 148.5 KB total

  const int t = threadIdx.x;
  const int lane = t & 63;
  const int w = t >> 6;          // wave 0..7 owns output cols w*64..+63
  const int bm = blockIdx.x;     // 256 blocks x 64 rows

  // A staging: thread t owns (row t>>3, 4-col seg t&7) of the 64x32 f32 subtile
  const float* pa = x + (size_t)(bm * 64 + (t >> 3)) * FEAT + (t & 7) * 4;
  const int aoff = (t >> 3) * LDA + (t & 7) * 4;

  // B staging: 4 gload_lds/thread/iter; call i covers rows i*128..+127.
  // LDS byte = i*8192 + w*1024 + lane*16 -> row = i*128 + w*16 + (lane>>2), dest chunk lane&3.
  // source chunk = (lane&3) ^ ((lane>>3)&3)  (XOR swizzle, verified R7/R8).
  const int brow = w * 16 + (lane >> 2);
  const int bc = (lane & 3) ^ ((lane >> 3) & 3);
  const _Float16* pb = Wh + (size_t)brow * FEAT + bc * 8;

  f32x4 acc[4][4] = {};
  f32x4 ra0, ra1;

  auto b_stage = [&](int k0, _Float16* dst) {
#pragma unroll
    for (int i = 0; i < 4; ++i)
      __builtin_amdgcn_global_load_lds((const AS1 void*)(pb + (size_t)i * 128 * FEAT + k0),
                                       (AS3 void*)((char*)dst + i * 8192 + w * 1024), 16, 0, 0);
  };
  auto a_write = [&](const f32x4& r, _Float16* labase) {
    half4v h;
    h[0] = (_Float16)r[0]; h[1] = (_Float16)r[1]; h[2] = (_Float16)r[2]; h[3] = (_Float16)r[3];
    *(half4v*)&labase[aoff] = h;
  };
  auto compute = [&](const _Float16* lb, const _Float16* la) {
    half8 af[4], bf[4];
#pragma unroll
    for (int i = 0; i < 4; ++i)
      af[i] = *(const half8*)&la[(i * 16 + (lane & 15)) * LDA + (lane >> 4) * 8];
#pragma unroll
    for (int j = 0; j < 4; ++j) {
      const int row = w * 64 + j * 16 + (lane & 15);
      const int cc = (lane >> 4) ^ ((lane >> 1) & 3);  // un-swizzle
      bf[j] = *(const half8*)&lb[row * 32 + cc * 8];
    }
#pragma unroll
    for (int i = 0; i < 4; ++i)
#pragma unroll
      for (int j = 0; j < 4; ++j)
        acc[i][j] = __builtin_amdgcn_mfma_f32_16x16x32_f16(af[i], bf[j], acc[i][j], 0, 0, 0);
  };

// iter KK: issue stage(KK+2) -> buf NXT, A(KK+2) -> RAI; compute buf CUR;
// a_write(KK+1) from RAW -> buf WBUF; counted wait; raw barrier.
#define STEP(KK, CUR, NXT, WBUF, RAW, RAI)                \
  b_stage(((KK) + 2) * 32, lB[NXT]);                      \
  RAI = *(const f32x4*)(pa + ((KK) + 2) * 32);            \
  compute(lB[CUR], lA[CUR]);                              \
  a_write(RAW, lA[WBUF]);                                 \
  VM5; LG0; BARX;

  // prologue: fill buf0/buf1
  b_stage(0, lB[0]);
  ra0 = *(const f32x4*)(pa + 0);
  b_stage(32, lB[1]);
  ra1 = *(const f32x4*)(pa + 32);
  VM5;                 // B(0), A(0) complete; B(1), A(1) still in flight
  a_write(ra0, lA[0]);
  LG0; BARX;

#pragma unroll 1
  for (int g = 0; g < 28; g += 4) {
    STEP(g + 0, 0, 2, 1, ra1, ra0)
    STEP(g + 1, 1, 3, 2, ra0, ra1)
    STEP(g + 2, 2, 0, 3, ra1, ra0)
    STEP(g + 3, 3, 1, 0, ra0, ra1)
  }
  STEP(28, 0, 2, 1, ra1, ra0)
  STEP(29, 1, 3, 2, ra0, ra1)
  // k=30: last stage already issued; drain everything, write A(31)
  compute(lB[2], lA[2]);
  VM0;
  a_write(ra1, lA[3]);
  LG0; BARX;
  // k=31
  compute(lB[3], lA[3]);

  // epilogue: bias + sigmoid, store f16 to heap position (col+1)&511
#pragma unroll
  for (int j = 0; j < 4; ++j) {
    const int col = w * 64 + j * 16 + (lane & 15);
    const float bb = (col < N_INNER) ? bias[col] : 0.f;
    const int hpos = (col + 1) & 511;
#pragma unroll
    for (int i = 0; i < 4; ++i) {
      const int rowb = bm * 64 + i * 16 + ((lane >> 4) << 2);
#pragma unroll
      for (int r = 0; r < 4; ++r) {
        float v = acc[i][j][r] + bb;
        v = 1.f / (1.f + __expf(-v));
        gates[(size_t)(rowb + r) * NPAD + hpos] = (_Float16)v;
      }
    }
  }
}

// ---------------- K2: tree expansion + GEMM2 (prob @ leaf_logits) ----------------
#define LPS 520

__global__ __launch_bounds__(512, 4) void k_tree(
    const _Float16* __restrict__ gates, const _Float16* __restrict__ LT,
    float* __restrict__ out) {
  __shared__ _Float16 lp[32 * LPS];

  const int t = threadIdx.x;
  const int rowl = t >> 4, sub = t & 15;
  const size_t grow = (size_t)blockIdx.x * 32 + rowl;
  const _Float16* g = gates + grow * NPAD;

  const float f0 = (float)g[1];
  const float f1 = (float)g[2 + (sub >> 3)];
  const float f2 = (float)g[4 + (sub >> 2)];
  const float f3 = (float)g[8 + (sub >> 1)];
  const _Float16 g4 = g[16 + sub];
  const half2v g5 = *(const half2v*)(g + 32 + 2 * sub);
  const half4v g6 = *(const half4v*)(g + 64 + 4 * sub);
  const half8 g7 = *(const half8*)(g + 128 + 8 * sub);
  const half8 g8a = *(const half8*)(g + 256 + 16 * sub);
  const half8 g8b = *(const half8*)(g + 256 + 16 * sub + 8);

  float p = ((sub & 8) ? f0 : 1.f - f0) * ((sub & 4) ? f1 : 1.f - f1) *
            ((sub & 2) ? f2 : 1.f - f2) * ((sub & 1) ? f3 : 1.f - f3);

  float arr[32];
  {
    const float gg = (float)g4;
    arr[1] = p * gg; arr[0] = p - p * gg;
  }
#pragma unroll
  for (int i = 1; i >= 0; --i) {
    const float gg = (float)g5[i];
    const float pp = arr[i];
    arr[2 * i + 1] = pp * gg; arr[2 * i] = pp - pp * gg;
  }
#pragma unroll
  for (int i = 3; i >= 0; --i) {
    const float gg = (float)g6[i];
    const float pp = arr[i];
    arr[2 * i + 1] = pp * gg; arr[2 * i] = pp - pp * gg;
  }
#pragma unroll
  for (int i = 7; i >= 0; --i) {
    const float gg = (float)g7[i];
    const float pp = arr[i];
    arr[2 * i + 1] = pp * gg; arr[2 * i] = pp - pp * gg;
  }
#pragma unroll
  for (int i = 15; i >= 0; --i) {
    const float gg = (i < 8) ? (float)g8a[i] : (float)g8b[i - 8];
    const float pp = arr[i];
    arr[2 * i + 1] = pp * gg; arr[2 * i] = pp - pp * gg;
  }

  const int lb = sub * 32;
#pragma unroll
  for (int i = 0; i < 32; i += 8) {
    half8 h;
#pragma unroll
    for (int jj = 0; jj < 8; ++jj) h[jj] = (_Float16)arr[i + jj];
    *(half8*)&lp[rowl * LPS + lb + i] = h;
  }
  __syncthreads();

  const int lane = t & 63, w = t >> 6;
  if (w < 7) {
    f32x4 acc[2] = {};
#pragma unroll
    for (int k0 = 0; k0 < 512; k0 += 32) {
      const int n = w * 16 + (lane & 15);
      const half8 b8 = *(const half8*)&LT[(size_t)n * NPAD + k0 + (lane >> 4) * 8];
#pragma unroll
      for (int mf = 0; mf < 2; ++mf) {
        const half8 a = *(const half8*)&lp[(mf * 16 + (lane & 15)) * LPS + k0 + (lane >> 4) * 8];
        acc[mf] = __builtin_amdgcn_mfma_f32_16x16x32_f16(a, b8, acc[mf], 0, 0, 0);
      }
    }

    const int col = w * 16 + (lane & 15);
    if (col < NCLS) {
#pragma unroll
      for (int mf = 0; mf < 2; ++mf) {
        const int rowb = blockIdx.x * 32 + mf * 16 + ((lane >> 4) << 2);
#pragma unroll
        for (int r = 0; r < 4; ++r)
          out[(size_t)(rowb + r) * NCLS + col] = acc[mf][r];
      }
    }
  }
}

extern "C" void kernel_launch(void* const* d_in, const int* in_sizes, int n_in,
                              void* d_out, int out_size, void* d_ws, size_t ws_size,
                              hipStream_t stream) {
  const float* x = (const float*)d_in[0];
  const float* W = (const float*)d_in[1];
  const float* b = (const float*)d_in[2];
  const float* L = (const float*)d_in[3];
  float* out = (float*)d_out;

  char* ws = (char*)d_ws;
  _Float16* Wh    = (_Float16*)ws;                 // 1 MB @ 0
  _Float16* LT    = (_Float16*)(ws + (1u << 20));  // 112 KB @ 1 MB
  _Float16* gates = (_Float16*)(ws + (2u << 20));  // 16 MB @ 2 MB

  k_prep<<<256, 256, 0, stream>>>(W, L, Wh, LT);
  k_gemm1<<<256, 512, 0, stream>>>(x, Wh, b, gates);
  k_tree<<<512, 512, 0, stream>>>(gates, LT, out);
}